// Round 4
// baseline (70.210 us; speedup 1.0000x reference)
//
#include <hip/hip_runtime.h>

namespace {

constexpr int NQ   = 10;    // qubits
constexpr int DIM  = 1024;  // 2^10 amplitudes
constexpr int NL   = 3;     // layers
constexpr int FEAT = 20;    // input features per sample
constexpr int S    = 32;    // batch
constexpr int APL  = 16;    // amplitudes per lane (64 lanes x 16 = 1024)

// amp_new = ca*s0 + cb*s1 (complex)
__device__ __forceinline__ float2 gate2(float2 ca, float2 s0, float2 cb, float2 s1) {
    float2 r;
    r.x = ca.x * s0.x - ca.y * s0.y + cb.x * s1.x - cb.y * s1.y;
    r.y = ca.x * s0.y + ca.y * s0.x + cb.x * s1.y + cb.y * s1.x;
    return r;
}

// One WAVE per sample; the full 1024-amplitude state lives in registers
// (16 float2 per lane). Amplitude index i = lane*16 + local:
//   local bits 0..3  = amplitude bits 0..3  (qubits 9,8,7,6) -> in-register gates
//   lane  bits 0..5  = amplitude bits 4..9  (qubits 5..0)    -> shfl_xor gates
// Zero __syncthreads: single-wave LDS round-trip handles the ring permutation
// (DS pipeline is in-order per wave). Single-qubit gates on distinct qubits
// commute, so per-layer gate order is free.
__global__ __launch_bounds__(64) void qsim(const float* __restrict__ X,
                                           const float* __restrict__ W,
                                           const float* __restrict__ Bb,
                                           float* __restrict__ out,
                                           int write_imag)
{
    const int s    = blockIdx.x;
    const int lane = threadIdx.x;   // 0..63

    __shared__ float2 gmat[NL * NQ][4];  // all 30 gate matrices
    __shared__ float2 pbuf[DIM];         // wave-private permutation scratch

    // --- all 30 Rot(phi,theta,omega) matrices, one per lane (lanes 0..29) ---
    if (lane < NL * NQ) {
        const int base = lane * 3;  // == l*30 + q*3 for g = lane = l*10+q
        const float phi   = X[s * FEAT + (base    ) % FEAT] * W[base    ] + Bb[base    ];
        const float theta = X[s * FEAT + (base + 1) % FEAT] * W[base + 1] + Bb[base + 1];
        const float omega = X[s * FEAT + (base + 2) % FEAT] * W[base + 2] + Bb[base + 2];
        float sn, ct;  sincosf(0.5f * theta,         &sn, &ct);
        float sp, cp;  sincosf(0.5f * (phi + omega), &sp, &cp);
        float sm, cm;  sincosf(0.5f * (phi - omega), &sm, &cm);
        gmat[lane][0] = make_float2( cp * ct, -sp * ct);  // m00
        gmat[lane][1] = make_float2(-cm * sn, -sm * sn);  // m01
        gmat[lane][2] = make_float2( cm * sn, -sm * sn);  // m10
        gmat[lane][3] = make_float2( cp * ct,  sp * ct);  // m11
    }
    // same wave writes & reads -> no barrier needed (in-order DS pipeline)

    // --- ring-CNOT gather indices: new[j] = old[r(j)] (verified vs reference) ---
    int rsrc[APL];
#pragma unroll
    for (int j = 0; j < APL; ++j) {
        int r = lane * APL + j;
        if (r & 1) r ^= 1 << 9;             // pair (9,0)
#pragma unroll
        for (int c = 8; c >= 0; --c)        // pair (c,c+1)
            if ((r >> (9 - c)) & 1) r ^= 1 << (8 - c);
        rsrc[j] = r;
    }

    // --- |0...0> ---
    float2 amp[APL];
#pragma unroll
    for (int j = 0; j < APL; ++j) amp[j] = make_float2(0.f, 0.f);
    if (lane == 0) amp[0] = make_float2(1.f, 0.f);

    for (int l = 0; l < NL; ++l) {
        // cross-lane gates: qubits 0..5 (amplitude bit 9-q, lane bit 5-q)
        for (int q = 0; q < 6; ++q) {
            const int g = l * NQ + q;
            const float2 m00 = gmat[g][0], m01 = gmat[g][1];
            const float2 m10 = gmat[g][2], m11 = gmat[g][3];
            const int  lb   = 5 - q;
            const int  mask = 1 << lb;
            const bool hi   = (lane >> lb) & 1;
            // self-coefficient / partner-coefficient per lane role:
            //   bit=0 lane: n0 = m00*self + m01*other
            //   bit=1 lane: n1 = m11*self + m10*other
            const float2 ca = hi ? m11 : m00;
            const float2 cb = hi ? m10 : m01;
#pragma unroll
            for (int j = 0; j < APL; ++j) {
                float2 o;
                o.x = __shfl_xor(amp[j].x, mask);
                o.y = __shfl_xor(amp[j].y, mask);
                amp[j] = gate2(ca, amp[j], cb, o);
            }
        }
        // in-register gates: qubits 6..9 (local bit 9-q), fully unrolled
#pragma unroll
        for (int q = 6; q < 10; ++q) {
            const int g = l * NQ + q;
            const float2 m00 = gmat[g][0], m01 = gmat[g][1];
            const float2 m10 = gmat[g][2], m11 = gmat[g][3];
            const int st = 1 << (9 - q);
#pragma unroll
            for (int p = 0; p < APL; ++p) {
                if (!(p & st)) {
                    const float2 a = amp[p], c = amp[p | st];
                    amp[p]      = gate2(m00, a, m01, c);
                    amp[p | st] = gate2(m10, a, m11, c);
                }
            }
        }
        // ring-CNOT permutation via wave-private LDS (no barrier: single wave)
#pragma unroll
        for (int j = 0; j < APL; ++j) pbuf[lane * APL + j] = amp[j];
#pragma unroll
        for (int j = 0; j < APL; ++j) amp[j] = pbuf[rsrc[j]];
    }

    // --- planar fp32 output: real plane, then (if present) imag plane ---
    const int base_o = s * DIM + lane * APL;
#pragma unroll
    for (int j = 0; j < APL; ++j) out[base_o + j] = amp[j].x;
    if (write_imag) {
#pragma unroll
        for (int j = 0; j < APL; ++j) out[S * DIM + base_o + j] = amp[j].y;
    }
}

} // namespace

extern "C" void kernel_launch(void* const* d_in, const int* in_sizes, int n_in,
                              void* d_out, int out_size, void* d_ws, size_t ws_size,
                              hipStream_t stream) {
    const float* X = (const float*)d_in[0];   // (32, 20) fp32
    const float* W = (const float*)d_in[1];   // (3, 10, 3) fp32
    const float* B = (const float*)d_in[2];   // (3, 10, 3) fp32
    (void)in_sizes; (void)n_in; (void)d_ws; (void)ws_size;
    const int write_imag = (out_size >= 2 * S * DIM) ? 1 : 0;
    qsim<<<S, 64, 0, stream>>>(X, W, B, (float*)d_out, write_imag);
}

// Round 5
// 69.306 us; speedup vs baseline: 1.0130x; 1.0130x over previous
//
#include <hip/hip_runtime.h>

namespace {

constexpr int NQ    = 10;    // qubits
constexpr int DIM   = 1024;  // 2^10 amplitudes
constexpr int NL    = 3;     // layers
constexpr int FEAT  = 20;    // input features per sample
constexpr int S     = 32;    // batch
constexpr int APL   = 16;    // amplitudes per lane (64 lanes x 16 = 1024)
constexpr int PITCH = 17;    // float2 pitch for perm buffer (bank swizzle)

// amp_new = ca*s0 + cb*s1 (complex)
__device__ __forceinline__ float2 gate2(float2 ca, float2 s0, float2 cb, float2 s1) {
    float2 r;
    r.x = ca.x * s0.x - ca.y * s0.y + cb.x * s1.x - cb.y * s1.y;
    r.y = ca.x * s0.y + ca.y * s0.x + cb.x * s1.y + cb.y * s1.x;
    return r;
}

// One WAVE per sample; full 1024-amp state in registers (16 float2/lane).
// i = lane*16 + local: local bits 0..3 = qubits 9..6 (in-register gates),
// lane bits 0..5 = qubits 5..0 (shfl_xor gates). Zero barriers (single-wave
// DS pipeline is in-order). Latency-oriented: per-layer batched coefficient
// preload, gather-then-compute shfl gates, bank-swizzled perm buffer.
__global__ __launch_bounds__(64) void qsim(const float* __restrict__ X,
                                           const float* __restrict__ W,
                                           const float* __restrict__ Bb,
                                           float* __restrict__ out,
                                           int write_imag)
{
    const int s    = blockIdx.x;
    const int lane = threadIdx.x;   // 0..63

    __shared__ float4 gmat[NL * NQ][2];   // [g][0]=(m00,m01), [g][1]=(m10,m11)
    __shared__ float2 pbuf[64 * PITCH];   // swizzled perm scratch (wave-private)

    // --- all 30 Rot matrices, one per lane (lanes 0..29) ---
    if (lane < NL * NQ) {
        const int base = lane * 3;
        const float phi   = X[s * FEAT + (base    ) % FEAT] * W[base    ] + Bb[base    ];
        const float theta = X[s * FEAT + (base + 1) % FEAT] * W[base + 1] + Bb[base + 1];
        const float omega = X[s * FEAT + (base + 2) % FEAT] * W[base + 2] + Bb[base + 2];
        float sn, ct;  sincosf(0.5f * theta,         &sn, &ct);
        float sp, cp;  sincosf(0.5f * (phi + omega), &sp, &cp);
        float sm, cm;  sincosf(0.5f * (phi - omega), &sm, &cm);
        gmat[lane][0] = make_float4(cp * ct, -sp * ct, -cm * sn, -sm * sn); // m00,m01
        gmat[lane][1] = make_float4(cm * sn, -sm * sn,  cp * ct,  sp * ct); // m10,m11
    }

    // --- ring-CNOT gather indices (verified vs reference), as swizzled slots ---
    int rslot[APL];
#pragma unroll
    for (int j = 0; j < APL; ++j) {
        int r = lane * APL + j;
        if (r & 1) r ^= 1 << 9;             // pair (9,0)
#pragma unroll
        for (int c = 8; c >= 0; --c)        // pair (c,c+1)
            if ((r >> (9 - c)) & 1) r ^= 1 << (8 - c);
        rslot[j] = (r >> 4) * PITCH + (r & 15);
    }

    // --- |0...0> ---
    float2 amp[APL];
#pragma unroll
    for (int j = 0; j < APL; ++j) amp[j] = make_float2(0.f, 0.f);
    if (lane == 0) amp[0] = make_float2(1.f, 0.f);

    for (int l = 0; l < NL; ++l) {
        // Batched preload of this layer's 10 gate matrices into registers.
        // Broadcast reads (same addr all lanes) -> no conflicts, one waitcnt.
        // Same-wave write->read: DS pipeline is in-order, no barrier needed.
        float4 cmA[NQ], cmB[NQ];
#pragma unroll
        for (int q = 0; q < NQ; ++q) {
            cmA[q] = gmat[l * NQ + q][0];
            cmB[q] = gmat[l * NQ + q][1];
        }

        // cross-lane gates: qubits 0..5 (lane bit 5-q), gather-then-compute
#pragma unroll
        for (int q = 0; q < 6; ++q) {
            const int  mask = 1 << (5 - q);
            const bool hi   = (lane & mask) != 0;
            const float2 m00 = make_float2(cmA[q].x, cmA[q].y);
            const float2 m01 = make_float2(cmA[q].z, cmA[q].w);
            const float2 m10 = make_float2(cmB[q].x, cmB[q].y);
            const float2 m11 = make_float2(cmB[q].z, cmB[q].w);
            const float2 ca  = hi ? m11 : m00;
            const float2 cb  = hi ? m10 : m01;
            float2 o[APL];
#pragma unroll
            for (int j = 0; j < APL; ++j) {           // issue all 32 shfls
                o[j].x = __shfl_xor(amp[j].x, mask);
                o[j].y = __shfl_xor(amp[j].y, mask);
            }
#pragma unroll
            for (int j = 0; j < APL; ++j)             // then compute
                amp[j] = gate2(ca, amp[j], cb, o[j]);
        }

        // in-register gates: qubits 6..9 (local bit 9-q), pure VALU
#pragma unroll
        for (int q = 6; q < 10; ++q) {
            const float2 m00 = make_float2(cmA[q].x, cmA[q].y);
            const float2 m01 = make_float2(cmA[q].z, cmA[q].w);
            const float2 m10 = make_float2(cmB[q].x, cmB[q].y);
            const float2 m11 = make_float2(cmB[q].z, cmB[q].w);
            const int st = 1 << (9 - q);
#pragma unroll
            for (int p = 0; p < APL; ++p) {
                if (!(p & st)) {
                    const float2 a = amp[p], c = amp[p | st];
                    amp[p]      = gate2(m00, a, m01, c);
                    amp[p | st] = gate2(m10, a, m11, c);
                }
            }
        }

        // ring-CNOT permutation via swizzled wave-private LDS (no barrier)
#pragma unroll
        for (int j = 0; j < APL; ++j) pbuf[lane * PITCH + j] = amp[j];
#pragma unroll
        for (int j = 0; j < APL; ++j) amp[j] = pbuf[rslot[j]];
    }

    // --- planar fp32 output: real plane, then (if present) imag plane ---
    const int base_o = s * DIM + lane * APL;
#pragma unroll
    for (int j = 0; j < APL; ++j) out[base_o + j] = amp[j].x;
    if (write_imag) {
#pragma unroll
        for (int j = 0; j < APL; ++j) out[S * DIM + base_o + j] = amp[j].y;
    }
}

} // namespace

extern "C" void kernel_launch(void* const* d_in, const int* in_sizes, int n_in,
                              void* d_out, int out_size, void* d_ws, size_t ws_size,
                              hipStream_t stream) {
    const float* X = (const float*)d_in[0];   // (32, 20) fp32
    const float* W = (const float*)d_in[1];   // (3, 10, 3) fp32
    const float* B = (const float*)d_in[2];   // (3, 10, 3) fp32
    (void)in_sizes; (void)n_in; (void)d_ws; (void)ws_size;
    const int write_imag = (out_size >= 2 * S * DIM) ? 1 : 0;
    qsim<<<S, 64, 0, stream>>>(X, W, B, (float*)d_out, write_imag);
}

// Round 6
// 62.143 us; speedup vs baseline: 1.1298x; 1.1153x over previous
//
#include <hip/hip_runtime.h>

namespace {

constexpr int NQ   = 10;    // qubits
constexpr int DIM  = 1024;  // 2^10 amplitudes
constexpr int NL   = 3;     // layers
constexpr int FEAT = 20;    // input features per sample
constexpr int S    = 32;    // batch
constexpr int APL  = 4;     // amplitudes per lane (4 waves x 64 lanes x 4)

__device__ __forceinline__ float2 cmul(float2 a, float2 b) {
    return make_float2(a.x * b.x - a.y * b.y, a.x * b.y + a.y * b.x);
}
__device__ __forceinline__ float2 cmad(float2 a, float2 b, float2 acc) {
    acc.x += a.x * b.x - a.y * b.y;
    acc.y += a.x * b.y + a.y * b.x;
    return acc;
}
// amp_new = ca*s0 + cb*s1 (complex)
__device__ __forceinline__ float2 gate2(float2 ca, float2 s0, float2 cb, float2 s1) {
    float2 r;
    r.x = ca.x * s0.x - ca.y * s0.y + cb.x * s1.x - cb.y * s1.y;
    r.y = ca.x * s0.y + ca.y * s0.x + cb.x * s1.y + cb.y * s1.x;
    return r;
}

// 4 waves per sample, 4 amps per lane. Amplitude i = wave*256 + j*64 + lane:
//   lane bits 0..5 = amp bits 0..5 = qubits 9..4  -> shfl_xor gates
//   j    bits 0..1 = amp bits 6..7 = qubits 3,2   -> in-register gates
//   wave bits 0..1 = amp bits 8..9 = qubits 1,0   -> fused (4x4 matrix) with
//                                                    the ring permutation in
//                                                    ONE LDS round-trip.
// 6 barriers total (vs 39 in the 512-thread version, vs 4500-inst serial
// stream in the 1-wave version). Gates on distinct qubits commute.
__global__ __launch_bounds__(256) void qsim(const float* __restrict__ X,
                                            const float* __restrict__ W,
                                            const float* __restrict__ Bb,
                                            float* __restrict__ out,
                                            int write_imag)
{
    const int s    = blockIdx.x;
    const int tid  = threadIdx.x;
    const int wave = tid >> 6;
    const int lane = tid & 63;

    __shared__ float2 gmat[NL * NQ][4];  // per-gate m00,m01,m10,m11
    __shared__ float2 M4[NL][16];        // fused (gate0 x gate1) 4x4 per layer
    __shared__ float2 pbuf[DIM];         // permutation scratch

    // --- ring-perm gather indices (verified vs reference): new[i] = old[r(i)] ---
    int rlow[APL], rrow[APL];
#pragma unroll
    for (int j = 0; j < APL; ++j) {
        int r = wave * 256 + j * 64 + lane;
        if (r & 1) r ^= 1 << 9;             // pair (9,0)
#pragma unroll
        for (int c = 8; c >= 0; --c)        // pair (c,c+1)
            if ((r >> (9 - c)) & 1) r ^= 1 << (8 - c);
        rlow[j] = r & 255;                  // amp bits 0..7 of source
        rrow[j] = r >> 8;                   // amp bits 8..9 -> M4 row
    }

    // --- wave 0 builds all 30 gate matrices, then the 3 fused 4x4s.
    // Both stages are within wave 0: per-wave in-order DS needs no barrier
    // between them (pattern HW-validated in rounds 3-5).
    if (tid < NL * NQ) {
        const int base = tid * 3;
        const float phi   = X[s * FEAT + (base    ) % FEAT] * W[base    ] + Bb[base    ];
        const float theta = X[s * FEAT + (base + 1) % FEAT] * W[base + 1] + Bb[base + 1];
        const float omega = X[s * FEAT + (base + 2) % FEAT] * W[base + 2] + Bb[base + 2];
        float sn, ct;  sincosf(0.5f * theta,         &sn, &ct);
        float sp, cp;  sincosf(0.5f * (phi + omega), &sp, &cp);
        float sm, cm;  sincosf(0.5f * (phi - omega), &sm, &cm);
        gmat[tid][0] = make_float2( cp * ct, -sp * ct);  // m00
        gmat[tid][1] = make_float2(-cm * sn, -sm * sn);  // m01
        gmat[tid][2] = make_float2( cm * sn, -sm * sn);  // m10
        gmat[tid][3] = make_float2( cp * ct,  sp * ct);  // m11
    }
    if (tid < NL * 16) {
        const int l = tid >> 4, e = tid & 15, r = e >> 2, k = e & 3;
        // M4[r][k] = g_q0[r_bit9][k_bit9] * g_q1[r_bit8][k_bit8]
        const float2 g0 = gmat[l * NQ + 0][(r >> 1) * 2 + (k >> 1)];
        const float2 g1 = gmat[l * NQ + 1][(r & 1) * 2 + (k & 1)];
        M4[l][e] = cmul(g0, g1);
    }
    __syncthreads();   // barrier 1: publish gmat + M4 to waves 1..3

    // --- |0...0> : global amp 0 lives at wave 0, j 0, lane 0 ---
    float2 amp[APL];
#pragma unroll
    for (int j = 0; j < APL; ++j) amp[j] = make_float2(0.f, 0.f);
    if (wave == 0 && lane == 0) amp[0] = make_float2(1.f, 0.f);

    for (int l = 0; l < NL; ++l) {
        // preload this layer's qubit-2..9 matrices (broadcast LDS reads)
        float2 g[8][4];
#pragma unroll
        for (int q = 2; q < 10; ++q) {
#pragma unroll
            for (int e = 0; e < 4; ++e) g[q - 2][e] = gmat[l * NQ + q][e];
        }

        // cross-lane gates: qubits 4..9 (lane bit 9-q), gather-then-compute
#pragma unroll
        for (int q = 4; q < 10; ++q) {
            const int  mask = 1 << (9 - q);
            const bool hi   = (lane & mask) != 0;
            const float2 ca = hi ? g[q - 2][3] : g[q - 2][0];  // m11 : m00
            const float2 cb = hi ? g[q - 2][2] : g[q - 2][1];  // m10 : m01
            float2 o[APL];
#pragma unroll
            for (int j = 0; j < APL; ++j) {
                o[j].x = __shfl_xor(amp[j].x, mask);
                o[j].y = __shfl_xor(amp[j].y, mask);
            }
#pragma unroll
            for (int j = 0; j < APL; ++j) amp[j] = gate2(ca, amp[j], cb, o[j]);
        }

        // in-register gates: qubit 3 (j bit 0) then qubit 2 (j bit 1)
        {
            const float2 m00 = g[1][0], m01 = g[1][1], m10 = g[1][2], m11 = g[1][3];
            float2 a, c;
            a = amp[0]; c = amp[1]; amp[0] = gate2(m00, a, m01, c); amp[1] = gate2(m10, a, m11, c);
            a = amp[2]; c = amp[3]; amp[2] = gate2(m00, a, m01, c); amp[3] = gate2(m10, a, m11, c);
        }
        {
            const float2 m00 = g[0][0], m01 = g[0][1], m10 = g[0][2], m11 = g[0][3];
            float2 a, c;
            a = amp[0]; c = amp[2]; amp[0] = gate2(m00, a, m01, c); amp[2] = gate2(m10, a, m11, c);
            a = amp[1]; c = amp[3]; amp[1] = gate2(m00, a, m01, c); amp[3] = gate2(m10, a, m11, c);
        }

        // fused qubit-0/1 gates + ring permutation via ONE LDS round-trip:
        // final[i] = sum_k M4[bits98(r(i))][k] * pre[(r(i)&255) | k<<8]
        if (l) __syncthreads();             // prior layer's gathers complete
#pragma unroll
        for (int j = 0; j < APL; ++j)
            pbuf[wave * 256 + j * 64 + lane] = amp[j];   // lane-stride-1: no conflicts
        __syncthreads();
#pragma unroll
        for (int j = 0; j < APL; ++j) {
            const float2* Mrow = &M4[l][rrow[j] * 4];
            float2 acc = make_float2(0.f, 0.f);
#pragma unroll
            for (int k = 0; k < 4; ++k)
                acc = cmad(Mrow[k], pbuf[rlow[j] + (k << 8)], acc);
            amp[j] = acc;
        }
    }

    // --- planar fp32 output, fully coalesced ---
    const int base_o = s * DIM + wave * 256 + lane;
#pragma unroll
    for (int j = 0; j < APL; ++j) out[base_o + j * 64] = amp[j].x;
    if (write_imag) {
#pragma unroll
        for (int j = 0; j < APL; ++j) out[S * DIM + base_o + j * 64] = amp[j].y;
    }
}

} // namespace

extern "C" void kernel_launch(void* const* d_in, const int* in_sizes, int n_in,
                              void* d_out, int out_size, void* d_ws, size_t ws_size,
                              hipStream_t stream) {
    const float* X = (const float*)d_in[0];   // (32, 20) fp32
    const float* W = (const float*)d_in[1];   // (3, 10, 3) fp32
    const float* B = (const float*)d_in[2];   // (3, 10, 3) fp32
    (void)in_sizes; (void)n_in; (void)d_ws; (void)ws_size;
    const int write_imag = (out_size >= 2 * S * DIM) ? 1 : 0;
    qsim<<<S, 256, 0, stream>>>(X, W, B, (float*)d_out, write_imag);
}

// Round 7
// 61.240 us; speedup vs baseline: 1.1465x; 1.0148x over previous
//
#include <hip/hip_runtime.h>

namespace {

constexpr int NQ   = 10;    // qubits
constexpr int DIM  = 1024;  // 2^10 amplitudes
constexpr int NL   = 3;     // layers
constexpr int FEAT = 20;    // input features per sample
constexpr int S    = 32;    // batch
constexpr int APL  = 4;     // amplitudes per lane (4 waves x 64 lanes x 4)
constexpr int NW   = 4;     // waves per block

__device__ __forceinline__ float2 cmul(float2 a, float2 b) {
    return make_float2(a.x * b.x - a.y * b.y, a.x * b.y + a.y * b.x);
}
__device__ __forceinline__ float2 cmad(float2 a, float2 b, float2 acc) {
    acc.x += a.x * b.x - a.y * b.y;
    acc.y += a.x * b.y + a.y * b.x;
    return acc;
}
// amp_new = ca*s0 + cb*s1 (complex)
__device__ __forceinline__ float2 gate2(float2 ca, float2 s0, float2 cb, float2 s1) {
    float2 r;
    r.x = ca.x * s0.x - ca.y * s0.y + cb.x * s1.x - cb.y * s1.y;
    r.y = ca.x * s0.y + ca.y * s0.x + cb.x * s1.y + cb.y * s1.x;
    return r;
}

// 4 waves per sample, 4 amps per lane. Amplitude i = wave*256 + j*64 + lane:
//   lane bits 0..5 = amp bits 0..5 = qubits 9..4  -> shfl_xor gates
//   j    bits 0..1 = amp bits 6..7 = qubits 3,2   -> in-register gates
//   wave bits 0..1 = amp bits 8..9 = qubits 1,0   -> fused (4x4 matrix) with
//                                                    the ring permutation.
// Latency-minimized: gate matrices built REDUNDANTLY per wave in wave-private
// LDS (no publish barrier; per-wave DS is in-order), double-buffered perm
// scratch (no pre-write barrier) -> 3 block barriers total.
__global__ __launch_bounds__(256) void qsim(const float* __restrict__ X,
                                            const float* __restrict__ W,
                                            const float* __restrict__ Bb,
                                            float* __restrict__ out,
                                            int write_imag)
{
    const int s    = blockIdx.x;
    const int tid  = threadIdx.x;
    const int wave = tid >> 6;
    const int lane = tid & 63;

    __shared__ float2 gm[NW][NL * NQ][4];  // wave-private gate matrices
    __shared__ float2 M4[NW][NL][16];      // wave-private fused (q0 x q1) 4x4
    __shared__ float2 pbuf[2][DIM];        // double-buffered perm scratch

    // --- per-wave redundant gate build: lanes 0..29 (no cross-wave dep) ---
    if (lane < NL * NQ) {
        const int base = lane * 3;
        const float phi   = X[s * FEAT + (base    ) % FEAT] * W[base    ] + Bb[base    ];
        const float theta = X[s * FEAT + (base + 1) % FEAT] * W[base + 1] + Bb[base + 1];
        const float omega = X[s * FEAT + (base + 2) % FEAT] * W[base + 2] + Bb[base + 2];
        float sn, ct;  sincosf(0.5f * theta,         &sn, &ct);
        float sp, cp;  sincosf(0.5f * (phi + omega), &sp, &cp);
        float sm, cm;  sincosf(0.5f * (phi - omega), &sm, &cm);
        gm[wave][lane][0] = make_float2( cp * ct, -sp * ct);  // m00
        gm[wave][lane][1] = make_float2(-cm * sn, -sm * sn);  // m01
        gm[wave][lane][2] = make_float2( cm * sn, -sm * sn);  // m10
        gm[wave][lane][3] = make_float2( cp * ct,  sp * ct);  // m11
    }
    // fused 4x4 for qubits 0,1: lanes 0..47, reads own wave's gm (in-order DS)
    if (lane < NL * 16) {
        const int l = lane >> 4, e = lane & 15, r = e >> 2, k = e & 3;
        const float2 g0 = gm[wave][l * NQ + 0][(r >> 1) * 2 + (k >> 1)];
        const float2 g1 = gm[wave][l * NQ + 1][(r & 1) * 2 + (k & 1)];
        M4[wave][l][e] = cmul(g0, g1);
    }
    // no barrier: every wave reads only its own gm/M4 copy.

    // --- ring-perm gather indices (verified vs reference): new[i] = old[r(i)] ---
    int rlow[APL], rrow[APL];
#pragma unroll
    for (int j = 0; j < APL; ++j) {
        int r = wave * 256 + j * 64 + lane;
        if (r & 1) r ^= 1 << 9;             // pair (9,0)
#pragma unroll
        for (int c = 8; c >= 0; --c)        // pair (c,c+1)
            if ((r >> (9 - c)) & 1) r ^= 1 << (8 - c);
        rlow[j] = r & 255;                  // source amp bits 0..7
        rrow[j] = r >> 8;                   // source amp bits 8..9 -> M4 row
    }

    // --- |0...0> ---
    float2 amp[APL];
#pragma unroll
    for (int j = 0; j < APL; ++j) amp[j] = make_float2(0.f, 0.f);
    if (wave == 0 && lane == 0) amp[0] = make_float2(1.f, 0.f);

    for (int l = 0; l < NL; ++l) {
        // cross-lane gates: qubits 4..9 (lane bit 9-q). Per-lane coefficient
        // pairs read directly by address (ca = hi?m11:m00, cb = hi?m10:m01).
#pragma unroll
        for (int q = 4; q < 10; ++q) {
            const int  mask = 1 << (9 - q);
            const int  hi   = (lane & mask) ? 1 : 0;
            const float2 ca = gm[wave][l * NQ + q][hi ? 3 : 0];
            const float2 cb = gm[wave][l * NQ + q][hi ? 2 : 1];
            float2 o[APL];
#pragma unroll
            for (int j = 0; j < APL; ++j) {           // issue all shfls
                o[j].x = __shfl_xor(amp[j].x, mask);
                o[j].y = __shfl_xor(amp[j].y, mask);
            }
#pragma unroll
            for (int j = 0; j < APL; ++j) amp[j] = gate2(ca, amp[j], cb, o[j]);
        }

        // in-register gates: qubit 3 (j bit 0), then qubit 2 (j bit 1)
        {
            const float2 m00 = gm[wave][l * NQ + 3][0], m01 = gm[wave][l * NQ + 3][1];
            const float2 m10 = gm[wave][l * NQ + 3][2], m11 = gm[wave][l * NQ + 3][3];
            float2 a, c;
            a = amp[0]; c = amp[1]; amp[0] = gate2(m00, a, m01, c); amp[1] = gate2(m10, a, m11, c);
            a = amp[2]; c = amp[3]; amp[2] = gate2(m00, a, m01, c); amp[3] = gate2(m10, a, m11, c);
        }
        {
            const float2 m00 = gm[wave][l * NQ + 2][0], m01 = gm[wave][l * NQ + 2][1];
            const float2 m10 = gm[wave][l * NQ + 2][2], m11 = gm[wave][l * NQ + 2][3];
            float2 a, c;
            a = amp[0]; c = amp[2]; amp[0] = gate2(m00, a, m01, c); amp[2] = gate2(m10, a, m11, c);
            a = amp[1]; c = amp[3]; amp[1] = gate2(m00, a, m01, c); amp[3] = gate2(m10, a, m11, c);
        }

        // fused qubit-0/1 gates + ring permutation, double-buffered:
        // final[i] = sum_k M4[bits98(r(i))][k] * pre[(r(i)&255) | k<<8]
        float2* buf = pbuf[l & 1];
#pragma unroll
        for (int j = 0; j < APL; ++j)
            buf[wave * 256 + j * 64 + lane] = amp[j];  // lane-stride-1: conflict-free
        __syncthreads();                               // the layer's only barrier
#pragma unroll
        for (int j = 0; j < APL; ++j) {
            const float2* Mrow = &M4[wave][l][rrow[j] * 4];
            float2 acc = make_float2(0.f, 0.f);
#pragma unroll
            for (int k = 0; k < 4; ++k)
                acc = cmad(Mrow[k], buf[rlow[j] + (k << 8)], acc);
            amp[j] = acc;
        }
    }

    // --- planar fp32 output, fully coalesced ---
    const int base_o = s * DIM + wave * 256 + lane;
#pragma unroll
    for (int j = 0; j < APL; ++j) out[base_o + j * 64] = amp[j].x;
    if (write_imag) {
#pragma unroll
        for (int j = 0; j < APL; ++j) out[S * DIM + base_o + j * 64] = amp[j].y;
    }
}

} // namespace

extern "C" void kernel_launch(void* const* d_in, const int* in_sizes, int n_in,
                              void* d_out, int out_size, void* d_ws, size_t ws_size,
                              hipStream_t stream) {
    const float* X = (const float*)d_in[0];   // (32, 20) fp32
    const float* W = (const float*)d_in[1];   // (3, 10, 3) fp32
    const float* B = (const float*)d_in[2];   // (3, 10, 3) fp32
    (void)in_sizes; (void)n_in; (void)d_ws; (void)ws_size;
    const int write_imag = (out_size >= 2 * S * DIM) ? 1 : 0;
    qsim<<<S, 256, 0, stream>>>(X, W, B, (float*)d_out, write_imag);
}

// Round 8
// 60.568 us; speedup vs baseline: 1.1592x; 1.0111x over previous
//
#include <hip/hip_runtime.h>

namespace {

constexpr int NQ   = 10;    // qubits
constexpr int DIM  = 1024;  // 2^10 amplitudes
constexpr int NL   = 3;     // layers
constexpr int FEAT = 20;    // input features per sample
constexpr int S    = 32;    // batch
constexpr int APL  = 4;     // amplitudes per lane (4 waves x 64 lanes x 4)
constexpr int NW   = 4;     // waves per block

__device__ __forceinline__ float2 cmul(float2 a, float2 b) {
    return make_float2(a.x * b.x - a.y * b.y, a.x * b.y + a.y * b.x);
}
__device__ __forceinline__ float2 cmad(float2 a, float2 b, float2 acc) {
    acc.x += a.x * b.x - a.y * b.y;
    acc.y += a.x * b.y + a.y * b.x;
    return acc;
}
// amp_new = ca*s0 + cb*s1 (complex)
__device__ __forceinline__ float2 gate2(float2 ca, float2 s0, float2 cb, float2 s1) {
    float2 r;
    r.x = ca.x * s0.x - ca.y * s0.y + cb.x * s1.x - cb.y * s1.y;
    r.y = ca.x * s0.y + ca.y * s0.x + cb.x * s1.y + cb.y * s1.x;
    return r;
}

// 4 waves per sample, 4 amps per lane. Amplitude i = wave*256 + j*64 + lane:
//   lane bits 0..5 = amp bits 0..5 = qubits 9..4  -> shfl_xor gates
//   j    bits 0..1 = amp bits 6..7 = qubits 3,2   -> in-register gates
//   wave bits 0..1 = amp bits 8..9 = qubits 1,0   -> fused (4x4 matrix) with
//                                                    the ring permutation.
// Latency-minimized: per-wave redundant gate build (no publish barrier),
// HW-native __sinf/__cosf (args in (-1,2): safe), layer 0 applied to |0..0>
// analytically (product of column-0 entries), double-buffered perm scratch.
// 3 block barriers total.
__global__ __launch_bounds__(256) void qsim(const float* __restrict__ X,
                                            const float* __restrict__ W,
                                            const float* __restrict__ Bb,
                                            float* __restrict__ out,
                                            int write_imag)
{
    const int s    = blockIdx.x;
    const int tid  = threadIdx.x;
    const int wave = tid >> 6;
    const int lane = tid & 63;

    __shared__ float2 gm[NW][NL * NQ][4];  // wave-private gate matrices
    __shared__ float2 M4[NW][NL][16];      // wave-private fused (q0 x q1) 4x4
    __shared__ float2 pbuf[2][DIM];        // double-buffered perm scratch

    // --- per-wave redundant gate build: lanes 0..29 (no cross-wave dep) ---
    if (lane < NL * NQ) {
        const int base = lane * 3;
        const float phi   = X[s * FEAT + (base    ) % FEAT] * W[base    ] + Bb[base    ];
        const float theta = X[s * FEAT + (base + 1) % FEAT] * W[base + 1] + Bb[base + 1];
        const float omega = X[s * FEAT + (base + 2) % FEAT] * W[base + 2] + Bb[base + 2];
        // args are in (-1, 2): HW-native sin/cos are plenty accurate here
        const float ht = 0.5f * theta, hp = 0.5f * (phi + omega), hm = 0.5f * (phi - omega);
        const float sn = __sinf(ht), ct = __cosf(ht);
        const float sp = __sinf(hp), cp = __cosf(hp);
        const float sm = __sinf(hm), cm = __cosf(hm);
        gm[wave][lane][0] = make_float2( cp * ct, -sp * ct);  // m00
        gm[wave][lane][1] = make_float2(-cm * sn, -sm * sn);  // m01
        gm[wave][lane][2] = make_float2( cm * sn, -sm * sn);  // m10
        gm[wave][lane][3] = make_float2( cp * ct,  sp * ct);  // m11
    }
    // fused 4x4 for qubits 0,1: reads own wave's gm (per-wave in-order DS)
    if (lane < NL * 16) {
        const int l = lane >> 4, e = lane & 15, r = e >> 2, k = e & 3;
        const float2 g0 = gm[wave][l * NQ + 0][(r >> 1) * 2 + (k >> 1)];
        const float2 g1 = gm[wave][l * NQ + 1][(r & 1) * 2 + (k & 1)];
        M4[wave][l][e] = cmul(g0, g1);
    }
    // no barrier: every wave reads only its own gm/M4 copy.

    // --- ring-perm gather indices (verified vs reference): new[i] = old[r(i)] ---
    int rlow[APL], rrow[APL];
#pragma unroll
    for (int j = 0; j < APL; ++j) {
        int r = wave * 256 + j * 64 + lane;
        if (r & 1) r ^= 1 << 9;             // pair (9,0)
#pragma unroll
        for (int c = 8; c >= 0; --c)        // pair (c,c+1)
            if ((r >> (9 - c)) & 1) r ^= 1 << (8 - c);
        rlow[j] = r & 255;                  // source amp bits 0..7
        rrow[j] = r >> 8;                   // source amp bits 8..9 -> M4 row
    }

    float2 amp[APL];

    // --- layer 0 on |0..0>, analytic: pre-M4 state is nonzero only on
    // wave 0 (qubit-0/1 bits of the source are 0), with
    //   amp[i] = prod_{q=2..9} m_q[bit_{9-q}(i)][0]
    // (column-0 entries: m00 = gm[..][0], m10 = gm[..][2]).
    if (wave == 0) {
        float2 p = make_float2(1.f, 0.f);
#pragma unroll
        for (int q = 4; q < 10; ++q) {      // lane-bit qubits
            const int b = (lane >> (9 - q)) & 1;
            p = cmul(p, gm[0][q][b ? 2 : 0]);
        }
        const float2 m3l = gm[0][3][0], m3h = gm[0][3][2];  // qubit 3 (j bit 0)
        const float2 m2l = gm[0][2][0], m2h = gm[0][2][2];  // qubit 2 (j bit 1)
        amp[0] = cmul(p, cmul(m3l, m2l));
        amp[1] = cmul(p, cmul(m3h, m2l));
        amp[2] = cmul(p, cmul(m3l, m2h));
        amp[3] = cmul(p, cmul(m3h, m2h));
    } else {
#pragma unroll
        for (int j = 0; j < APL; ++j) amp[j] = make_float2(0.f, 0.f);
    }

    for (int l = 0; l < NL; ++l) {
        if (l > 0) {
            // cross-lane gates: qubits 4..9 (lane bit 9-q)
#pragma unroll
            for (int q = 4; q < 10; ++q) {
                const int  mask = 1 << (9 - q);
                const int  hi   = (lane & mask) ? 1 : 0;
                const float2 ca = gm[wave][l * NQ + q][hi ? 3 : 0];
                const float2 cb = gm[wave][l * NQ + q][hi ? 2 : 1];
                float2 o[APL];
#pragma unroll
                for (int j = 0; j < APL; ++j) {       // issue all shfls
                    o[j].x = __shfl_xor(amp[j].x, mask);
                    o[j].y = __shfl_xor(amp[j].y, mask);
                }
#pragma unroll
                for (int j = 0; j < APL; ++j) amp[j] = gate2(ca, amp[j], cb, o[j]);
            }
            // in-register gates: qubit 3 (j bit 0), then qubit 2 (j bit 1)
            {
                const float2 m00 = gm[wave][l * NQ + 3][0], m01 = gm[wave][l * NQ + 3][1];
                const float2 m10 = gm[wave][l * NQ + 3][2], m11 = gm[wave][l * NQ + 3][3];
                float2 a, c;
                a = amp[0]; c = amp[1]; amp[0] = gate2(m00, a, m01, c); amp[1] = gate2(m10, a, m11, c);
                a = amp[2]; c = amp[3]; amp[2] = gate2(m00, a, m01, c); amp[3] = gate2(m10, a, m11, c);
            }
            {
                const float2 m00 = gm[wave][l * NQ + 2][0], m01 = gm[wave][l * NQ + 2][1];
                const float2 m10 = gm[wave][l * NQ + 2][2], m11 = gm[wave][l * NQ + 2][3];
                float2 a, c;
                a = amp[0]; c = amp[2]; amp[0] = gate2(m00, a, m01, c); amp[2] = gate2(m10, a, m11, c);
                a = amp[1]; c = amp[3]; amp[1] = gate2(m00, a, m01, c); amp[3] = gate2(m10, a, m11, c);
            }
        }

        // fused qubit-0/1 gates + ring permutation, double-buffered:
        // final[i] = sum_k M4[bits98(r(i))][k] * pre[(r(i)&255) | k<<8]
        float2* buf = pbuf[l & 1];
#pragma unroll
        for (int j = 0; j < APL; ++j)
            buf[wave * 256 + j * 64 + lane] = amp[j];  // lane-stride-1: conflict-free
        __syncthreads();                               // the layer's only barrier
#pragma unroll
        for (int j = 0; j < APL; ++j) {
            const float2* Mrow = &M4[wave][l][rrow[j] * 4];
            float2 acc = make_float2(0.f, 0.f);
#pragma unroll
            for (int k = 0; k < 4; ++k)
                acc = cmad(Mrow[k], buf[rlow[j] + (k << 8)], acc);
            amp[j] = acc;
        }
    }

    // --- planar fp32 output, fully coalesced ---
    const int base_o = s * DIM + wave * 256 + lane;
#pragma unroll
    for (int j = 0; j < APL; ++j) out[base_o + j * 64] = amp[j].x;
    if (write_imag) {
#pragma unroll
        for (int j = 0; j < APL; ++j) out[S * DIM + base_o + j * 64] = amp[j].y;
    }
}

} // namespace

extern "C" void kernel_launch(void* const* d_in, const int* in_sizes, int n_in,
                              void* d_out, int out_size, void* d_ws, size_t ws_size,
                              hipStream_t stream) {
    const float* X = (const float*)d_in[0];   // (32, 20) fp32
    const float* W = (const float*)d_in[1];   // (3, 10, 3) fp32
    const float* B = (const float*)d_in[2];   // (3, 10, 3) fp32
    (void)in_sizes; (void)n_in; (void)d_ws; (void)ws_size;
    const int write_imag = (out_size >= 2 * S * DIM) ? 1 : 0;
    qsim<<<S, 256, 0, stream>>>(X, W, B, (float*)d_out, write_imag);
}